// Round 1
// baseline (233.066 us; speedup 1.0000x reference)
//
#include <hip/hip_runtime.h>
#include <stdint.h>

#define N_Q   65536
#define N_S   65536
#define NB_H  26
#define PAD_H 28
#define KP    10
#define CIN   64
#define COUT  128
#define MT    32   // query points per block

typedef unsigned int   u32x4  __attribute__((ext_vector_type(4)));
typedef unsigned short u16x8  __attribute__((ext_vector_type(8)));
typedef float          f32x4  __attribute__((ext_vector_type(4)));
typedef __bf16         bf16x8 __attribute__((ext_vector_type(8)));

static __device__ __forceinline__ unsigned short f2bf(float f) {
  unsigned int u = __float_as_uint(f);
  u += 0x7fffu + ((u >> 16) & 1u);          // round-to-nearest-even
  return (unsigned short)(u >> 16);
}
static __device__ __forceinline__ float bf2f(unsigned short h) {
  return __uint_as_float(((unsigned int)h) << 16);
}

// ---- prep 1: x fp32 -> bf16 -------------------------------------------------
__global__ void cvt_x_kernel(const float* __restrict__ x,
                             unsigned short* __restrict__ xb) {
  int t = blockIdx.x * blockDim.x + threadIdx.x;   // one thread per 8 elems
  long off = (long)t * 8;
  if (off >= (long)N_S * CIN) return;
  f32x4 a = *(const f32x4*)(x + off);
  f32x4 b = *(const f32x4*)(x + off + 4);
  u16x8 o;
  o[0] = f2bf(a[0]); o[1] = f2bf(a[1]); o[2] = f2bf(a[2]); o[3] = f2bf(a[3]);
  o[4] = f2bf(b[0]); o[5] = f2bf(b[1]); o[6] = f2bf(b[2]); o[7] = f2bf(b[3]);
  *(u16x8*)(xb + off) = o;
}

// ---- prep 2: pack weights [640][128] fp32 -> MFMA B-fragment order bf16 -----
// Bpack[((ct*20 + ks)*64 + lane)*8 + j] = B[ks*32 + (lane>>4)*8 + j][ct*16 + (lane&15)]
__global__ void pack_w_kernel(const float* __restrict__ w,
                              unsigned short* __restrict__ bp) {
  int t = blockIdx.x * blockDim.x + threadIdx.x;
  if (t >= 8 * 20 * 64) return;
  int lane = t & 63;
  int frag = t >> 6;            // ct*20 + ks
  int ks = frag % 20;
  int ct = frag / 20;
  int row0 = ks * 32 + (lane >> 4) * 8;
  int col  = ct * 16 + (lane & 15);
  u16x8 o;
  #pragma unroll
  for (int j = 0; j < 8; ++j) o[j] = f2bf(w[(row0 + j) * COUT + col]);
  *(u16x8*)(bp + (long)t * 8) = o;
}

// ---- main fused kernel ------------------------------------------------------
__global__ void __launch_bounds__(256, 2)
kpconv_main(const float* __restrict__ q_pts, const float* __restrict__ s_pts,
            const float* __restrict__ gen_W, const float* __restrict__ gen_b,
            const int* __restrict__ inds, const unsigned short* __restrict__ xb,
            const unsigned short* __restrict__ bp, float* __restrict__ out) {

  __shared__ int            sh_ind[MT][NB_H];          //  3328 B
  __shared__ float          sh_nbr[MT][NB_H][3];       //  9984 B
  __shared__ float          sh_kp[MT][KP * 3];         //  3840 B
  __shared__ unsigned short sh_aw[MT][KP * NB_H];      // 16640 B
  __shared__ unsigned short sh_w[MT][648];             // 41472 B (pad 640->648)

  const int tid  = threadIdx.x;
  const int base = blockIdx.x * MT;

  // ---- Phase A: neighbors = s_pad[ind] - q ----
  for (int p = tid; p < MT * NB_H; p += 256) {
    int m = p / NB_H, h = p % NB_H;
    int n = base + m;
    int ind = inds[n * NB_H + h];
    sh_ind[m][h] = ind;
    float sx, sy, sz;
    if ((unsigned)ind < (unsigned)N_S) {
      sx = s_pts[ind * 3 + 0]; sy = s_pts[ind * 3 + 1]; sz = s_pts[ind * 3 + 2];
    } else {
      sx = 1e6f; sy = 1e6f; sz = 1e6f;   // shadow support point
    }
    sh_nbr[m][h][0] = sx - q_pts[n * 3 + 0];
    sh_nbr[m][h][1] = sy - q_pts[n * 3 + 1];
    sh_nbr[m][h][2] = sz - q_pts[n * 3 + 2];
  }
  __syncthreads();

  // ---- Phase A2: kernel points kp = padded @ gen_W^T + gen_b ----
  // padding slots (H..PAD_H) are constant -1 -> folded into bias.
  for (int p = tid; p < MT * KP * 3; p += 256) {
    int m = p / (KP * 3), r = p % (KP * 3);
    const float* Wr = gen_W + r * (PAD_H * 3);
    float acc = gen_b[r];
    #pragma unroll
    for (int c = NB_H * 3; c < PAD_H * 3; ++c) acc -= Wr[c];
    for (int h = 0; h < NB_H; ++h) {
      acc += Wr[h * 3 + 0] * sh_nbr[m][h][0]
           + Wr[h * 3 + 1] * sh_nbr[m][h][1]
           + Wr[h * 3 + 2] * sh_nbr[m][h][2];
    }
    sh_kp[m][r] = acc;
  }
  __syncthreads();

  // ---- Phase B: all_w[m][k][h] = max(1 - |nbr - kp| / 1.2, 0) ----
  for (int p = tid; p < MT * KP * NB_H; p += 256) {
    int m = p / (KP * NB_H);
    int r = p - m * (KP * NB_H);
    int k = r / NB_H, h = r % NB_H;
    float dx = sh_nbr[m][h][0] - sh_kp[m][k * 3 + 0];
    float dy = sh_nbr[m][h][1] - sh_kp[m][k * 3 + 1];
    float dz = sh_nbr[m][h][2] - sh_kp[m][k * 3 + 2];
    float d  = sqrtf(dx * dx + dy * dy + dz * dz);
    float w  = fmaxf(1.0f - d * (1.0f / 1.2f), 0.0f);
    sh_aw[m][k * NB_H + h] = f2bf(w);
  }
  __syncthreads();

  // ---- Phase C: weighted[m][k][i] = sum_h all_w[m][k][h] * x[ind[m][h]][i] ----
  // 8 threads per point, 8 channels each.
  {
    int m  = tid >> 3;
    int i0 = (tid & 7) * 8;
    float acc[KP][8];
    #pragma unroll
    for (int k = 0; k < KP; ++k)
      #pragma unroll
      for (int j = 0; j < 8; ++j) acc[k][j] = 0.0f;

    for (int h = 0; h < NB_H; ++h) {
      int ind = sh_ind[m][h];
      float xv[8];
      if ((unsigned)ind < (unsigned)N_S) {
        u16x8 xi = *(const u16x8*)(xb + (long)ind * CIN + i0);
        #pragma unroll
        for (int j = 0; j < 8; ++j) xv[j] = bf2f(xi[j]);
      } else {
        #pragma unroll
        for (int j = 0; j < 8; ++j) xv[j] = 0.0f;   // shadow feature row = 0
      }
      #pragma unroll
      for (int k = 0; k < KP; ++k) {
        float w = bf2f(sh_aw[m][k * NB_H + h]);
        #pragma unroll
        for (int j = 0; j < 8; ++j) acc[k][j] = fmaf(w, xv[j], acc[k][j]);
      }
    }
    #pragma unroll
    for (int k = 0; k < KP; ++k) {
      u16x8 o;
      #pragma unroll
      for (int j = 0; j < 8; ++j) o[j] = f2bf(acc[k][j]);
      *(u16x8*)&sh_w[m][k * CIN + i0] = o;
    }
  }
  __syncthreads();

  // ---- Phase D: out[32][128] = weighted[32][640] @ B[640][128] via MFMA ----
  {
    const int wave = tid >> 6;
    const int lane = tid & 63;
    const int arow = lane & 15;
    const int ak   = (lane >> 4) * 8;
    const int ct0  = wave * 2, ct1 = ct0 + 1;
    f32x4 acc00 = {0.f, 0.f, 0.f, 0.f}, acc01 = {0.f, 0.f, 0.f, 0.f};
    f32x4 acc10 = {0.f, 0.f, 0.f, 0.f}, acc11 = {0.f, 0.f, 0.f, 0.f};
    for (int ks = 0; ks < 20; ++ks) {
      u16x8 a0u = *(const u16x8*)&sh_w[arow][ks * 32 + ak];
      u16x8 a1u = *(const u16x8*)&sh_w[16 + arow][ks * 32 + ak];
      u16x8 b0u = *(const u16x8*)(bp + (long)((ct0 * 20 + ks) * 64 + lane) * 8);
      u16x8 b1u = *(const u16x8*)(bp + (long)((ct1 * 20 + ks) * 64 + lane) * 8);
      bf16x8 a0 = __builtin_bit_cast(bf16x8, a0u);
      bf16x8 a1 = __builtin_bit_cast(bf16x8, a1u);
      bf16x8 b0 = __builtin_bit_cast(bf16x8, b0u);
      bf16x8 b1 = __builtin_bit_cast(bf16x8, b1u);
      acc00 = __builtin_amdgcn_mfma_f32_16x16x32_bf16(a0, b0, acc00, 0, 0, 0);
      acc01 = __builtin_amdgcn_mfma_f32_16x16x32_bf16(a0, b1, acc01, 0, 0, 0);
      acc10 = __builtin_amdgcn_mfma_f32_16x16x32_bf16(a1, b0, acc10, 0, 0, 0);
      acc11 = __builtin_amdgcn_mfma_f32_16x16x32_bf16(a1, b1, acc11, 0, 0, 0);
    }
    // C/D layout: col = lane&15, row = (lane>>4)*4 + reg  [measured m89/m91]
    const int col   = lane & 15;
    const int rbase = (lane >> 4) * 4;
    #pragma unroll
    for (int r = 0; r < 4; ++r) {
      out[(long)(base + rbase + r) * COUT + ct0 * 16 + col]      = acc00[r];
      out[(long)(base + rbase + r) * COUT + ct1 * 16 + col]      = acc01[r];
      out[(long)(base + 16 + rbase + r) * COUT + ct0 * 16 + col] = acc10[r];
      out[(long)(base + 16 + rbase + r) * COUT + ct1 * 16 + col] = acc11[r];
    }
  }
}

extern "C" void kernel_launch(void* const* d_in, const int* in_sizes, int n_in,
                              void* d_out, int out_size, void* d_ws, size_t ws_size,
                              hipStream_t stream) {
  const float* q_pts = (const float*)d_in[0];
  const float* s_pts = (const float*)d_in[1];
  const float* x     = (const float*)d_in[2];
  const float* gen_W = (const float*)d_in[3];
  const float* gen_b = (const float*)d_in[4];
  const float* wts   = (const float*)d_in[5];
  const int*   inds  = (const int*)d_in[6];
  float* out = (float*)d_out;

  unsigned short* xb = (unsigned short*)d_ws;            // N_S*CIN bf16 = 8 MiB
  unsigned short* bp = xb + (size_t)N_S * CIN;           // 81920 bf16 = 160 KiB

  int cvt_threads = (N_S * CIN) / 8;                     // 524288
  cvt_x_kernel<<<(cvt_threads + 255) / 256, 256, 0, stream>>>(x, xb);
  pack_w_kernel<<<40, 256, 0, stream>>>(wts, bp);
  kpconv_main<<<N_Q / MT, 256, 0, stream>>>(q_pts, s_pts, gen_W, gen_b,
                                            inds, xb, bp, out);
}

// Round 2
// 196.667 us; speedup vs baseline: 1.1851x; 1.1851x over previous
//
#include <hip/hip_runtime.h>
#include <stdint.h>

#define N_Q   65536
#define N_S   65536
#define NB_H  26
#define PAD_H 28
#define KP    10
#define CIN   64
#define COUT  128
#define MT    16   // query points per block

typedef unsigned short u16x4  __attribute__((ext_vector_type(4)));
typedef unsigned short u16x8  __attribute__((ext_vector_type(8)));
typedef float          f32x4  __attribute__((ext_vector_type(4)));
typedef __bf16         bf16x8 __attribute__((ext_vector_type(8)));

static __device__ __forceinline__ unsigned short f2bf(float f) {
  unsigned int u = __float_as_uint(f);
  u += 0x7fffu + ((u >> 16) & 1u);          // round-to-nearest-even
  return (unsigned short)(u >> 16);
}
static __device__ __forceinline__ float bf2f(unsigned short h) {
  return __uint_as_float(((unsigned int)h) << 16);
}

// ---- prep 1: x fp32 -> bf16, plus zeroed shadow row at index N_S ------------
__global__ void cvt_x_kernel(const float* __restrict__ x,
                             unsigned short* __restrict__ xb) {
  long t = (long)blockIdx.x * blockDim.x + threadIdx.x;   // one thread per 8 elems
  long off = t * 8;
  if (off >= (long)(N_S + 1) * CIN) return;
  u16x8 o;
  if (off < (long)N_S * CIN) {
    f32x4 a = *(const f32x4*)(x + off);
    f32x4 b = *(const f32x4*)(x + off + 4);
    o[0] = f2bf(a[0]); o[1] = f2bf(a[1]); o[2] = f2bf(a[2]); o[3] = f2bf(a[3]);
    o[4] = f2bf(b[0]); o[5] = f2bf(b[1]); o[6] = f2bf(b[2]); o[7] = f2bf(b[3]);
  } else {
    o = (u16x8)0;                       // shadow feature row = zeros
  }
  *(u16x8*)(xb + off) = o;
}

// ---- prep 2: pack weights [640][128] fp32 -> MFMA B-fragment order bf16 -----
// Bpack[((ct*20 + ks)*64 + lane)*8 + j] = B[ks*32 + (lane>>4)*8 + j][ct*16 + (lane&15)]
__global__ void pack_w_kernel(const float* __restrict__ w,
                              unsigned short* __restrict__ bp) {
  int t = blockIdx.x * blockDim.x + threadIdx.x;
  if (t >= 8 * 20 * 64) return;
  int lane = t & 63;
  int frag = t >> 6;            // ct*20 + ks
  int ks = frag % 20;
  int ct = frag / 20;
  int row0 = ks * 32 + (lane >> 4) * 8;
  int col  = ct * 16 + (lane & 15);
  u16x8 o;
  #pragma unroll
  for (int j = 0; j < 8; ++j) o[j] = f2bf(w[(row0 + j) * COUT + col]);
  *(u16x8*)(bp + (long)t * 8) = o;
}

// ---- main fused kernel ------------------------------------------------------
// LDS: sh_ind 1664 + sh_aw 16640 + pool(max(sh_w 20736, nbr 4992 + kp 1920))
//    = 39040 B -> 4 blocks/CU (vs 75 KB / 2 blocks in round 1)
__global__ void __launch_bounds__(256, 4)
kpconv_main(const float* __restrict__ q_pts, const float* __restrict__ s_pts,
            const float* __restrict__ gen_W, const float* __restrict__ gen_b,
            const int* __restrict__ inds, const unsigned short* __restrict__ xb,
            const unsigned short* __restrict__ bp, float* __restrict__ out) {

  __shared__ int   sh_ind[MT][NB_H];              //  1664 B
  __shared__ float sh_aw[MT][KP * NB_H];          // 16640 B (fp32: no bf2f in hot loop)
  __shared__ __align__(16) char pool[MT * 648 * 2];  // 20736 B

  // overlapping views: nbr/kp are dead before sh_w is written (barrier between)
  float* sh_nbr = (float*)pool;                      // [MT][NB_H][3] = 4992 B
  float* sh_kp  = (float*)(pool + MT * NB_H * 3 * 4);// [MT][KP*3]   = 1920 B
  unsigned short* sh_w = (unsigned short*)pool;      // [MT][648]    = 20736 B

  const int tid  = threadIdx.x;
  const int base = blockIdx.x * MT;

  // ---- Phase A: neighbors = s_pad[ind] - q ----
  for (int p = tid; p < MT * NB_H; p += 256) {
    int m = p / NB_H, h = p % NB_H;
    int n = base + m;
    int ind = inds[n * NB_H + h];
    sh_ind[m][h] = ind;
    float sx, sy, sz;
    if ((unsigned)ind < (unsigned)N_S) {
      sx = s_pts[ind * 3 + 0]; sy = s_pts[ind * 3 + 1]; sz = s_pts[ind * 3 + 2];
    } else {
      sx = 1e6f; sy = 1e6f; sz = 1e6f;   // shadow support point
    }
    sh_nbr[(m * NB_H + h) * 3 + 0] = sx - q_pts[n * 3 + 0];
    sh_nbr[(m * NB_H + h) * 3 + 1] = sy - q_pts[n * 3 + 1];
    sh_nbr[(m * NB_H + h) * 3 + 2] = sz - q_pts[n * 3 + 2];
  }
  __syncthreads();

  // ---- Phase A2: kernel points kp = padded @ gen_W^T + gen_b ----
  // padding slots (H..PAD_H) are constant -1 -> folded into bias.
  for (int p = tid; p < MT * KP * 3; p += 256) {
    int m = p / (KP * 3), r = p % (KP * 3);
    const float* Wr = gen_W + r * (PAD_H * 3);
    float acc = gen_b[r];
    #pragma unroll
    for (int c = NB_H * 3; c < PAD_H * 3; ++c) acc -= Wr[c];
    for (int h = 0; h < NB_H; ++h) {
      acc += Wr[h * 3 + 0] * sh_nbr[(m * NB_H + h) * 3 + 0]
           + Wr[h * 3 + 1] * sh_nbr[(m * NB_H + h) * 3 + 1]
           + Wr[h * 3 + 2] * sh_nbr[(m * NB_H + h) * 3 + 2];
    }
    sh_kp[m * KP * 3 + r] = acc;
  }
  __syncthreads();

  // ---- Phase B: all_w[m][k][h] = max(1 - |nbr - kp| / 1.2, 0) (kept fp32) ----
  for (int p = tid; p < MT * KP * NB_H; p += 256) {
    int m = p / (KP * NB_H);
    int r = p - m * (KP * NB_H);
    int k = r / NB_H, h = r % NB_H;
    float dx = sh_nbr[(m * NB_H + h) * 3 + 0] - sh_kp[m * KP * 3 + k * 3 + 0];
    float dy = sh_nbr[(m * NB_H + h) * 3 + 1] - sh_kp[m * KP * 3 + k * 3 + 1];
    float dz = sh_nbr[(m * NB_H + h) * 3 + 2] - sh_kp[m * KP * 3 + k * 3 + 2];
    float d  = sqrtf(dx * dx + dy * dy + dz * dz);
    sh_aw[m][k * NB_H + h] = fmaxf(1.0f - d * (1.0f / 1.2f), 0.0f);
  }
  __syncthreads();

  // ---- Phase C: weighted[m][k][i] = sum_h all_w[m][k][h] * x[ind[m][h]][i] ----
  // 16 threads per point, 4 channels each; 2-deep explicit prefetch of x rows.
  {
    const int m  = tid >> 4;
    const int i0 = (tid & 15) * 4;
    float acc[KP][4];
    #pragma unroll
    for (int k = 0; k < KP; ++k)
      #pragma unroll
      for (int j = 0; j < 4; ++j) acc[k][j] = 0.0f;

    int ind0 = sh_ind[m][0];
    int ind1 = sh_ind[m][1];
    u16x4 xv0 = *(const u16x4*)(xb + (long)ind0 * CIN + i0);
    u16x4 xv1 = *(const u16x4*)(xb + (long)ind1 * CIN + i0);

    for (int h = 0; h < NB_H; ++h) {
      u16x4 xc = xv0;
      xv0 = xv1;
      int hp = h + 2; if (hp > NB_H - 1) hp = NB_H - 1;
      int indp = sh_ind[m][hp];
      xv1 = *(const u16x4*)(xb + (long)indp * CIN + i0);

      float xf0 = bf2f(xc[0]), xf1 = bf2f(xc[1]);
      float xf2 = bf2f(xc[2]), xf3 = bf2f(xc[3]);
      #pragma unroll
      for (int k = 0; k < KP; ++k) {
        float w = sh_aw[m][k * NB_H + h];
        acc[k][0] = fmaf(w, xf0, acc[k][0]);
        acc[k][1] = fmaf(w, xf1, acc[k][1]);
        acc[k][2] = fmaf(w, xf2, acc[k][2]);
        acc[k][3] = fmaf(w, xf3, acc[k][3]);
      }
    }
    __syncthreads();   // nbr/kp fully consumed; pool may now become sh_w
    #pragma unroll
    for (int k = 0; k < KP; ++k) {
      u16x4 o;
      #pragma unroll
      for (int j = 0; j < 4; ++j) o[j] = f2bf(acc[k][j]);
      *(u16x4*)&sh_w[m * 648 + k * CIN + i0] = o;
    }
  }
  __syncthreads();

  // ---- Phase D: out[16][128] = weighted[16][640] @ B[640][128] via MFMA ----
  {
    const int wave = tid >> 6;
    const int lane = tid & 63;
    const int arow = lane & 15;
    const int ak   = (lane >> 4) * 8;
    const int ct0  = wave * 2, ct1 = ct0 + 1;
    f32x4 acc0 = {0.f, 0.f, 0.f, 0.f}, acc1 = {0.f, 0.f, 0.f, 0.f};
    for (int ks = 0; ks < 20; ++ks) {
      u16x8 au  = *(const u16x8*)&sh_w[arow * 648 + ks * 32 + ak];
      u16x8 b0u = *(const u16x8*)(bp + (long)((ct0 * 20 + ks) * 64 + lane) * 8);
      u16x8 b1u = *(const u16x8*)(bp + (long)((ct1 * 20 + ks) * 64 + lane) * 8);
      bf16x8 a  = __builtin_bit_cast(bf16x8, au);
      bf16x8 b0 = __builtin_bit_cast(bf16x8, b0u);
      bf16x8 b1 = __builtin_bit_cast(bf16x8, b1u);
      acc0 = __builtin_amdgcn_mfma_f32_16x16x32_bf16(a, b0, acc0, 0, 0, 0);
      acc1 = __builtin_amdgcn_mfma_f32_16x16x32_bf16(a, b1, acc1, 0, 0, 0);
    }
    // C/D layout: col = lane&15, row = (lane>>4)*4 + reg  [measured m89/m91]
    const int col   = lane & 15;
    const int rbase = (lane >> 4) * 4;
    #pragma unroll
    for (int r = 0; r < 4; ++r) {
      out[(long)(base + rbase + r) * COUT + ct0 * 16 + col] = acc0[r];
      out[(long)(base + rbase + r) * COUT + ct1 * 16 + col] = acc1[r];
    }
  }
}

extern "C" void kernel_launch(void* const* d_in, const int* in_sizes, int n_in,
                              void* d_out, int out_size, void* d_ws, size_t ws_size,
                              hipStream_t stream) {
  const float* q_pts = (const float*)d_in[0];
  const float* s_pts = (const float*)d_in[1];
  const float* x     = (const float*)d_in[2];
  const float* gen_W = (const float*)d_in[3];
  const float* gen_b = (const float*)d_in[4];
  const float* wts   = (const float*)d_in[5];
  const int*   inds  = (const int*)d_in[6];
  float* out = (float*)d_out;

  unsigned short* xb = (unsigned short*)d_ws;            // (N_S+1)*CIN bf16
  unsigned short* bp = xb + (size_t)(N_S + 1) * CIN;     // 81920 bf16 = 160 KiB

  long cvt_elems = (long)(N_S + 1) * CIN / 8;            // 524296
  cvt_x_kernel<<<(int)((cvt_elems + 255) / 256), 256, 0, stream>>>(x, xb);
  pack_w_kernel<<<40, 256, 0, stream>>>(wts, bp);
  kpconv_main<<<N_Q / MT, 256, 0, stream>>>(q_pts, s_pts, gen_W, gen_b,
                                            inds, xb, bp, out);
}